// Round 13
// baseline (282.628 us; speedup 1.0000x reference)
//
#include <hip/hip_runtime.h>
#include <math.h>

#define BB 2
#define CC 96
#define DIN 192
#define NST 16
#define RNK 6
#define KK 4
#define LL 4096
#define RTOT (RNK + 2*NST)   // 38

// Scratch layouts:
//   xc_pre (aliases y_scan), z_silu, xconv : [b][l_spatial][DIN]
//   xconvT : [b][tp(l)][DIN]  (transposed image, for k=1/3 contiguous scans)
//   dts    : [bk][p_scan][8]  (6 used)
//   Bs, Cs : [bk][p_scan][NST]
//   segA(/hinit alias)/segB : [bk][seg][d][NST]
//   y_scan : [bk][p_scan][DIN]  (scan-position order; k_final inverts analytically)
//
// Analytic scan index maps (verified against _make_ids):
//   k=0: spatial = p          k=1: spatial = p1[p], xs row in xconvT = p
//   k=2: spatial = LL-1-p     k=3: xs row in xconvT = LL-1-p
//   inverse (spatial l -> p): k=0: l; k=1: tp(l); k=2: LL-1-l; k=3: LL-1-tp(l)
//   tp(l) = (l&63)*64 + (l>>6)

// ---------------------------------------------------------------------------
// K1: in_proj. grid (L/32, B, z). Block 256 = 8 lg (4 l) x 32 og (6 oc).
__global__ __launch_bounds__(256) void k_inproj(const float* __restrict__ x,
        const float* __restrict__ W_in, float* __restrict__ xc_pre,
        float* __restrict__ z_silu) {
    __shared__ float lx[96*33];
    __shared__ float wt[48*196];
    int b = blockIdx.y, z = blockIdx.z;
    int l0 = blockIdx.x * 32;
    int t = threadIdx.x;
    for (int i = 0; i < 3; ++i) {
        int e4 = t + 256*i;              // 768 float4 = 32l x 24c4
        int c4 = e4 % 24, l = e4 / 24;
        float4 v = *(const float4*)&x[((size_t)(b*LL + l0 + l))*96 + 4*c4];
        lx[(4*c4+0)*33 + l] = v.x;
        lx[(4*c4+1)*33 + l] = v.y;
        lx[(4*c4+2)*33 + l] = v.z;
        lx[(4*c4+3)*33 + l] = v.w;
    }
    int lg = t & 7;
    int og = t >> 3;
    float acc[4][6];
    #pragma unroll
    for (int j = 0; j < 4; ++j)
        #pragma unroll
        for (int q = 0; q < 6; ++q) acc[j][q] = 0.f;
    for (int p = 0; p < 2; ++p) {
        __syncthreads();
        for (int i = 0; i < 9; ++i) {
            int e4 = t + 256*i;
            int cc4 = e4 % 12, oc = e4 / 12;
            float4 v = *(const float4*)&W_in[((size_t)(z*192 + oc))*96 + p*48 + 4*cc4];
            wt[(4*cc4+0)*196 + oc] = v.x;
            wt[(4*cc4+1)*196 + oc] = v.y;
            wt[(4*cc4+2)*196 + oc] = v.z;
            wt[(4*cc4+3)*196 + oc] = v.w;
        }
        __syncthreads();
        #pragma unroll 4
        for (int cc = 0; cc < 48; ++cc) {
            int c = p*48 + cc;
            float x0 = lx[c*33 + 4*lg + 0];
            float x1 = lx[c*33 + 4*lg + 1];
            float x2 = lx[c*33 + 4*lg + 2];
            float x3 = lx[c*33 + 4*lg + 3];
            const float* wr = &wt[cc*196 + 6*og];
            float2 w0 = *(const float2*)(wr);
            float2 w1 = *(const float2*)(wr + 2);
            float2 w2 = *(const float2*)(wr + 4);
            float wv[6] = {w0.x,w0.y, w1.x,w1.y, w2.x,w2.y};
            #pragma unroll
            for (int q = 0; q < 6; ++q) {
                acc[0][q] += x0*wv[q];
                acc[1][q] += x1*wv[q];
                acc[2][q] += x2*wv[q];
                acc[3][q] += x3*wv[q];
            }
        }
    }
    float* dst = (z == 0) ? xc_pre : z_silu;
    #pragma unroll
    for (int j = 0; j < 4; ++j) {
        int l = l0 + 4*lg + j;
        size_t base = (size_t)(b*LL + l)*DIN + 6*og;
        float v[6];
        #pragma unroll
        for (int q = 0; q < 6; ++q) {
            float a = acc[j][q];
            v[q] = z ? a/(1.f + __expf(-a)) : a;
        }
        *(float2*)&dst[base]     = make_float2(v[0], v[1]);
        *(float2*)&dst[base + 2] = make_float2(v[2], v[3]);
        *(float2*)&dst[base + 4] = make_float2(v[4], v[5]);
    }
}

// ---------------------------------------------------------------------------
// K2: depthwise 3x3 conv + bias + SiLU; writes BOTH spatial and transposed
// layouts (768 B contiguous row chunks in each).
__global__ __launch_bounds__(256) void k_conv(const float* __restrict__ xc,
        const float* __restrict__ cw, const float* __restrict__ cb,
        float* __restrict__ out, float* __restrict__ outT) {
    int gid = blockIdx.x*256 + threadIdx.x;    // B*L*48
    int dq = gid % 48;
    int r = gid / 48;
    int l = r & 4095, b = r >> 12;
    int w = l & 63, h = l >> 6;
    int d0 = dq*4;
    float4 acc = *(const float4*)&cb[d0];
    float wreg[4][9];
    #pragma unroll
    for (int j = 0; j < 4; ++j)
        #pragma unroll
        for (int tp = 0; tp < 9; ++tp) wreg[j][tp] = cw[(d0+j)*9 + tp];
    #pragma unroll
    for (int dh = -1; dh <= 1; ++dh) {
        int h2 = h + dh;
        bool okh = (h2 >= 0) && (h2 < 64);
        #pragma unroll
        for (int dw = -1; dw <= 1; ++dw) {
            int w2 = w + dw;
            if (okh && w2 >= 0 && w2 < 64) {
                float4 v = *(const float4*)&xc[((size_t)(b*LL + h2*64 + w2))*DIN + d0];
                int tp = (dh+1)*3 + (dw+1);
                acc.x += v.x*wreg[0][tp];
                acc.y += v.y*wreg[1][tp];
                acc.z += v.z*wreg[2][tp];
                acc.w += v.w*wreg[3][tp];
            }
        }
    }
    float4 o;
    o.x = acc.x/(1.f + __expf(-acc.x));
    o.y = acc.y/(1.f + __expf(-acc.y));
    o.z = acc.z/(1.f + __expf(-acc.z));
    o.w = acc.w/(1.f + __expf(-acc.w));
    *(float4*)&out[((size_t)(b*LL + l))*DIN + d0] = o;
    int lt = w*64 + h;                         // tp(l)
    *(float4*)&outT[((size_t)(b*LL + lt))*DIN + d0] = o;
}

// ---------------------------------------------------------------------------
// K3: x_proj GEMV -> dts + Bs/Cs. Analytic contiguous gather (no scan_ids).
__global__ __launch_bounds__(512) void k_proj(const float* __restrict__ xconv,
        const float* __restrict__ xconvT, const float* __restrict__ xpw,
        float* __restrict__ dts, float* __restrict__ Bs, float* __restrict__ Cs) {
    __shared__ float lxs[96*65];
    __shared__ float lw[RTOT*96];
    __shared__ float lbc[64*33];
    int k = blockIdx.y, b = blockIdx.z;
    int l0 = blockIdx.x * 64;
    int t = threadIdx.x;
    const float* src = (k & 1) ? xconvT : xconv;
    int rb = (k < 2) ? l0 : (LL - 1 - l0);
    int rs = (k < 2) ? 1 : -1;
    int l = t & 63;
    int rg = __builtin_amdgcn_readfirstlane(t >> 6);
    float acc[5];
    #pragma unroll
    for (int j = 0; j < 5; ++j) acc[j] = 0.f;
    for (int p = 0; p < 2; ++p) {
        __syncthreads();
        for (int i = 0; i < 3; ++i) {
            int e4 = t + 512*i;              // 1536 float4 = 64l x 24dd4
            int dd4 = e4 % 24, ll = e4 / 24;
            int row = rb + rs*ll;
            float4 v = *(const float4*)&src[((size_t)(b*LL + row))*DIN + p*96 + 4*dd4];
            lxs[(4*dd4+0)*65 + ll] = v.x;
            lxs[(4*dd4+1)*65 + ll] = v.y;
            lxs[(4*dd4+2)*65 + ll] = v.z;
            lxs[(4*dd4+3)*65 + ll] = v.w;
        }
        for (int i = 0; i < 2; ++i) {
            int e4 = t + 512*i;              // 912 float4 = 38r x 24dd4
            if (e4 < RTOT*24) {
                int r = e4 / 24, dd4 = e4 % 24;
                *(float4*)&lw[r*96 + 4*dd4] =
                    *(const float4*)&xpw[(size_t)k*RTOT*DIN + r*DIN + p*96 + 4*dd4];
            }
        }
        __syncthreads();
        for (int dd = 0; dd < 96; dd += 4) {
            float x0 = lxs[(dd+0)*65 + l];
            float x1 = lxs[(dd+1)*65 + l];
            float x2 = lxs[(dd+2)*65 + l];
            float x3 = lxs[(dd+3)*65 + l];
            #pragma unroll
            for (int j = 0; j < 5; ++j) {
                int r = rg + 8*j;
                if (r < RTOT) {
                    float4 w = *(const float4*)&lw[r*96 + dd];
                    acc[j] += x0*w.x + x1*w.y + x2*w.z + x3*w.w;
                }
            }
        }
    }
    int bk = b*KK + k;
    #pragma unroll
    for (int j = 0; j < 5; ++j) {
        int r = rg + 8*j;
        if (r < RNK)       dts[((size_t)bk*LL + l0 + l)*8 + r] = acc[j];
        else if (r < RTOT) lbc[l*33 + (r - RNK)] = acc[j];
    }
    __syncthreads();
    size_t rowb = ((size_t)bk*LL + l0)*NST;
    for (int i = 0; i < 2; ++i) {
        int e = t + 512*i;
        int n = e & 15, ll = e >> 4;
        Bs[rowb + ll*NST + n] = lbc[ll*33 + n];
        Cs[rowb + ll*NST + n] = lbc[ll*33 + 16 + n];
    }
}

// ---------------------------------------------------------------------------
// K4: heavy scan pass (h0 = 0). Fully streaming: x from xconv/xconvT with
// analytic ±1 row stride; y written in scan order. Fast power-tree path.
__global__ __launch_bounds__(384) void k_scan1(const float* __restrict__ xconv,
        const float* __restrict__ xconvT,
        const float* __restrict__ Bs, const float* __restrict__ Cs,
        const float* __restrict__ dts, const float* __restrict__ dtw,
        const float* __restrict__ dtb,
        const float* __restrict__ A_logs, const float* __restrict__ Ds,
        float* __restrict__ y_scan, float* __restrict__ segA,
        float* __restrict__ segB, int SL) {
    int seg = blockIdx.x, bk = blockIdx.y;
    int b = bk >> 2, k = bk & 3;
    int t = threadIdx.x;
    int half = t & 1, d = t >> 1;
    int l0 = seg * SL;
    const float* src = (k & 1) ? xconvT : xconv;
    int rb = (k < 2) ? l0 : (LL - 1 - l0);
    int rs = (k < 2) ? 1 : -1;
    float Av[8];
    {
        const float4* ap = (const float4*)(A_logs + ((k*DIN + d)*NST + half*8));
        float4 a0 = ap[0], a1 = ap[1];
        Av[0]=-__expf(a0.x); Av[1]=-__expf(a0.y); Av[2]=-__expf(a0.z); Av[3]=-__expf(a0.w);
        Av[4]=-__expf(a1.x); Av[5]=-__expf(a1.y); Av[6]=-__expf(a1.z); Av[7]=-__expf(a1.w);
    }
    float Av0 = -__expf(A_logs[(k*DIN + d)*NST]);
    bool okl = true;
    #pragma unroll
    for (int q = 0; q < 8; ++q) {
        float m = (float)(half*8 + q + 1);
        okl = okl && (fabsf(Av[q] - m*Av0) <= 1e-4f*m);
    }
    int fast = __all(okl);
    float Dv = Ds[k*DIN + d];
    float wdt[RNK];
    float bdt = dtb[k*DIN + d];
    #pragma unroll
    for (int r = 0; r < RNK; ++r) wdt[r] = dtw[(k*DIN + d)*RNK + r];
    float h[8];
    #pragma unroll
    for (int n = 0; n < 8; ++n) h[n] = 0.f;
    float sumdv = 0.f;
    const float* dbase = dts + ((size_t)bk*LL + l0)*8;
    const float* bbase = Bs + ((size_t)bk*LL + l0)*NST + half*8;
    const float* cbase = Cs + ((size_t)bk*LL + l0)*NST + half*8;
    float xn = src[((size_t)(b*LL + rb))*DIN + d];
    float drc[RNK];
    #pragma unroll
    for (int r = 0; r < RNK; ++r) drc[r] = dbase[r];
    float4 bn0 = *(const float4*)bbase,      bn1 = *(const float4*)(bbase + 4);
    float4 cn0 = *(const float4*)cbase,      cn1 = *(const float4*)(cbase + 4);
    if (fast) {
        for (int li = 0; li < SL; ++li) {
            float xv = xn;
            float drv[RNK];
            #pragma unroll
            for (int r = 0; r < RNK; ++r) drv[r] = drc[r];
            float4 b0 = bn0, b1 = bn1, c0v = cn0, c1v = cn1;
            if (li + 1 < SL) {
                int row = rb + rs*(li + 1);
                xn = src[((size_t)(b*LL + row))*DIN + d];
                #pragma unroll
                for (int r = 0; r < RNK; ++r) drc[r] = dbase[(li+1)*8 + r];
                bn0 = *(const float4*)(bbase + (size_t)(li+1)*NST);
                bn1 = *(const float4*)(bbase + (size_t)(li+1)*NST + 4);
                cn0 = *(const float4*)(cbase + (size_t)(li+1)*NST);
                cn1 = *(const float4*)(cbase + (size_t)(li+1)*NST + 4);
            }
            float aa = bdt;
            #pragma unroll
            for (int r = 0; r < RNK; ++r) aa += drv[r]*wdt[r];
            float dv = fmaxf(aa, 0.f) + __logf(1.f + __expf(-fabsf(aa)));
            sumdv += dv;
            float dxv = dv * xv;
            float bb[8] = {b0.x,b0.y,b0.z,b0.w, b1.x,b1.y,b1.z,b1.w};
            float cc[8] = {c0v.x,c0v.y,c0v.z,c0v.w, c1v.x,c1v.y,c1v.z,c1v.w};
            float E  = __expf(dv * Av0);
            float E2 = E*E, E4 = E2*E2;
            float P[8];
            P[0] = E;      P[1] = E2;     P[2] = E2*E;    P[3] = E4;
            P[4] = E4*E;   P[5] = E4*E2;  P[6] = E4*P[2]; P[7] = E4*E4;
            float s = half ? P[7] : 1.0f;
            float y = 0.f;
            #pragma unroll
            for (int n = 0; n < 8; ++n) {
                h[n] = (s*P[n])*h[n] + dxv*bb[n];
                y += h[n]*cc[n];
            }
            y += __shfl_xor(y, 1);
            if (half == 0) {
                y += xv * Dv;
                y_scan[((size_t)(bk*LL + l0 + li))*DIN + d] = y;   // partial
            }
        }
    } else {
        for (int li = 0; li < SL; ++li) {
            float xv = xn;
            float drv[RNK];
            #pragma unroll
            for (int r = 0; r < RNK; ++r) drv[r] = drc[r];
            float4 b0 = bn0, b1 = bn1, c0v = cn0, c1v = cn1;
            if (li + 1 < SL) {
                int row = rb + rs*(li + 1);
                xn = src[((size_t)(b*LL + row))*DIN + d];
                #pragma unroll
                for (int r = 0; r < RNK; ++r) drc[r] = dbase[(li+1)*8 + r];
                bn0 = *(const float4*)(bbase + (size_t)(li+1)*NST);
                bn1 = *(const float4*)(bbase + (size_t)(li+1)*NST + 4);
                cn0 = *(const float4*)(cbase + (size_t)(li+1)*NST);
                cn1 = *(const float4*)(cbase + (size_t)(li+1)*NST + 4);
            }
            float aa = bdt;
            #pragma unroll
            for (int r = 0; r < RNK; ++r) aa += drv[r]*wdt[r];
            float dv = fmaxf(aa, 0.f) + __logf(1.f + __expf(-fabsf(aa)));
            sumdv += dv;
            float dxv = dv * xv;
            float bb[8] = {b0.x,b0.y,b0.z,b0.w, b1.x,b1.y,b1.z,b1.w};
            float cc[8] = {c0v.x,c0v.y,c0v.z,c0v.w, c1v.x,c1v.y,c1v.z,c1v.w};
            float y = 0.f;
            #pragma unroll
            for (int n = 0; n < 8; ++n) {
                float e2 = __expf(dv * Av[n]);
                h[n] = e2*h[n] + dxv*bb[n];
                y += h[n]*cc[n];
            }
            y += __shfl_xor(y, 1);
            if (half == 0) {
                y += xv * Dv;
                y_scan[((size_t)(bk*LL + l0 + li))*DIN + d] = y;   // partial
            }
        }
    }
    float a[8];
    #pragma unroll
    for (int n = 0; n < 8; ++n) a[n] = __expf(Av[n]*sumdv);
    size_t base = (((size_t)bk*gridDim.x + seg)*DIN + d)*NST + half*8;
    *(float4*)&segA[base]     = make_float4(a[0],a[1],a[2],a[3]);
    *(float4*)&segA[base + 4] = make_float4(a[4],a[5],a[6],a[7]);
    *(float4*)&segB[base]     = make_float4(h[0],h[1],h[2],h[3]);
    *(float4*)&segB[base + 4] = make_float4(h[4],h[5],h[6],h[7]);
}

// ---------------------------------------------------------------------------
// K5: compose segment carries (hinit aliases segA) + zero poolsum.
__global__ __launch_bounds__(256) void k_scan2(const float* segA,
        const float* segB, float* hinit, float* poolsum, int SEGC) {
    int idx = blockIdx.x*256 + threadIdx.x;
    if (idx < BB*DIN*KK) poolsum[idx] = 0.f;
    if (idx >= BB*KK*DIN*NST) return;
    int bk = idx / (DIN*NST);
    int dn = idx % (DIN*NST);
    const size_t stride = DIN*NST;
    size_t o = (size_t)bk*SEGC*stride + dn;
    float h = 0.f;
    for (int s = 0; s < SEGC; s += 8) {
        float av[8], bv[8];
        #pragma unroll
        for (int j = 0; j < 8; ++j) {
            av[j] = segA[o + j*stride];
            bv[j] = segB[o + j*stride];
        }
        #pragma unroll
        for (int j = 0; j < 8; ++j) {
            hinit[o + j*stride] = h;
            h = av[j]*h + bv[j];
        }
        o += 8*stride;
    }
}

// ---------------------------------------------------------------------------
// K6: h0 correction, fully streaming (y_scan RMW contiguous):
//   y[p] += sum_n C[p,n]*h0[n]*exp(Av[n]*cum[p]).
__global__ __launch_bounds__(384) void k_apply(const float* __restrict__ Cs,
        const float* __restrict__ dts, const float* __restrict__ dtw,
        const float* __restrict__ dtb,
        const float* __restrict__ A_logs, const float* __restrict__ hinit,
        float* __restrict__ y_scan, float* __restrict__ poolsum, int SL) {
    int seg = blockIdx.x, bk = blockIdx.y;
    int b = bk >> 2, k = bk & 3;
    int t = threadIdx.x;
    int half = t & 1, d = t >> 1;
    int l0 = seg * SL;
    float Av[8];
    {
        const float4* ap = (const float4*)(A_logs + ((k*DIN + d)*NST + half*8));
        float4 a0 = ap[0], a1 = ap[1];
        Av[0]=-__expf(a0.x); Av[1]=-__expf(a0.y); Av[2]=-__expf(a0.z); Av[3]=-__expf(a0.w);
        Av[4]=-__expf(a1.x); Av[5]=-__expf(a1.y); Av[6]=-__expf(a1.z); Av[7]=-__expf(a1.w);
    }
    float Av0 = -__expf(A_logs[(k*DIN + d)*NST]);
    bool okl = true;
    #pragma unroll
    for (int q = 0; q < 8; ++q) {
        float m = (float)(half*8 + q + 1);
        okl = okl && (fabsf(Av[q] - m*Av0) <= 1e-4f*m);
    }
    int fast = __all(okl);
    float h0[8];
    {
        size_t base = (((size_t)bk*gridDim.x + seg)*DIN + d)*NST + half*8;
        float4 v0 = *(const float4*)&hinit[base];
        float4 v1 = *(const float4*)&hinit[base + 4];
        h0[0]=v0.x; h0[1]=v0.y; h0[2]=v0.z; h0[3]=v0.w;
        h0[4]=v1.x; h0[5]=v1.y; h0[6]=v1.z; h0[7]=v1.w;
    }
    float wdt[RNK];
    float bdt = dtb[k*DIN + d];
    #pragma unroll
    for (int r = 0; r < RNK; ++r) wdt[r] = dtw[(k*DIN + d)*RNK + r];
    float cum = 0.f;
    float pool = 0.f;
    const float* dbase = dts + ((size_t)bk*LL + l0)*8;
    const float* cbase = Cs + ((size_t)bk*LL + l0)*NST + half*8;
    float drc[RNK];
    #pragma unroll
    for (int r = 0; r < RNK; ++r) drc[r] = dbase[r];
    float4 cn0 = *(const float4*)cbase, cn1 = *(const float4*)(cbase + 4);
    for (int li = 0; li < SL; ++li) {
        float drv[RNK];
        #pragma unroll
        for (int r = 0; r < RNK; ++r) drv[r] = drc[r];
        float4 c0v = cn0, c1v = cn1;
        if (li + 1 < SL) {
            #pragma unroll
            for (int r = 0; r < RNK; ++r) drc[r] = dbase[(li+1)*8 + r];
            cn0 = *(const float4*)(cbase + (size_t)(li+1)*NST);
            cn1 = *(const float4*)(cbase + (size_t)(li+1)*NST + 4);
        }
        float aa = bdt;
        #pragma unroll
        for (int r = 0; r < RNK; ++r) aa += drv[r]*wdt[r];
        cum += fmaxf(aa, 0.f) + __logf(1.f + __expf(-fabsf(aa)));
        float cc[8] = {c0v.x,c0v.y,c0v.z,c0v.w, c1v.x,c1v.y,c1v.z,c1v.w};
        float g;
        if (fast) {
            float E = __expf(Av0 * cum);
            g = 0.f;
            #pragma unroll
            for (int q = 7; q >= 0; --q) g = g*E + cc[q]*h0[q];
            g *= E;
            if (half) {
                float E2 = E*E, E4 = E2*E2;
                g *= E4*E4;
            }
        } else {
            g = 0.f;
            #pragma unroll
            for (int q = 0; q < 8; ++q)
                g += cc[q]*h0[q]*__expf(Av[q]*cum);
        }
        g += __shfl_xor(g, 1);
        if (half == 0) {
            size_t yo = ((size_t)(bk*LL + l0 + li))*DIN + d;
            float y = y_scan[yo] + g;
            y_scan[yo] = y;
            pool += y;
        }
    }
    if (half == 0) atomicAdd(&poolsum[(b*DIN + d)*KK + k], pool);
}

// ---------------------------------------------------------------------------
// K7: gather y_scan via analytic inverse maps, gate, LN, silu(z), @ W_out^T.
__global__ __launch_bounds__(256) void k_final(const float* __restrict__ y_scan,
        const float* __restrict__ poolsum, const float* __restrict__ gw,
        const float* __restrict__ gb, const float* __restrict__ z_silu,
        const float* __restrict__ lng, const float* __restrict__ lnb,
        const float* __restrict__ Wout, float* __restrict__ out) {
    __shared__ float buf[16*196];
    __shared__ float lgate[DIN*KK];
    __shared__ float lwout[96*100];
    __shared__ float lmu[16], lrs[16];
    int b = blockIdx.y;
    int l0 = blockIdx.x * 16;
    int t = threadIdx.x;
    for (int e = t; e < DIN*KK; e += 256) {
        int d = e >> 2, o = e & 3;
        float acc = gb[d*KK + o];
        #pragma unroll
        for (int i = 0; i < KK; ++i)
            acc += (poolsum[(b*DIN + d)*KK + i] * (1.f/LL)) * gw[(d*KK + o)*KK + i];
        lgate[d*KK + o] = 1.f/(1.f + __expf(-acc));
    }
    __syncthreads();
    for (int i = 0; i < 3; ++i) {
        int e4 = t + 256*i;              // 768 = 16l x 48 d4
        int d4 = e4 % 48, l = e4 / 48;
        int db = 4*d4;
        int ls = l0 + l;
        int tpl = ((ls & 63) << 6) | (ls >> 6);
        int pk[4] = {ls, tpl, LL - 1 - ls, LL - 1 - tpl};
        float4 acc = make_float4(0.f, 0.f, 0.f, 0.f);
        #pragma unroll
        for (int k = 0; k < KK; ++k) {
            float4 v = *(const float4*)&y_scan[((size_t)((b*KK + k)*LL + pk[k]))*DIN + db];
            acc.x += v.x * lgate[(db+0)*KK + k];
            acc.y += v.y * lgate[(db+1)*KK + k];
            acc.z += v.z * lgate[(db+2)*KK + k];
            acc.w += v.w * lgate[(db+3)*KK + k];
        }
        *(float4*)&buf[l*196 + db] = acc;
    }
    __syncthreads();
    int l2 = t >> 4, q = t & 15;
    float s = 0.f, s2 = 0.f;
    for (int i = 0; i < 12; ++i) {
        float v = buf[l2*196 + q + 16*i];
        s += v; s2 += v*v;
    }
    s += __shfl_xor(s, 1);  s2 += __shfl_xor(s2, 1);
    s += __shfl_xor(s, 2);  s2 += __shfl_xor(s2, 2);
    s += __shfl_xor(s, 4);  s2 += __shfl_xor(s2, 4);
    s += __shfl_xor(s, 8);  s2 += __shfl_xor(s2, 8);
    if (q == 0) {
        float mu = s * (1.f/DIN);
        float var = s2 * (1.f/DIN) - mu*mu;
        lmu[l2] = mu;
        lrs[l2] = rsqrtf(var + 1e-5f);
    }
    __syncthreads();
    for (int i = 0; i < 3; ++i) {
        int e4 = t + 256*i;
        int d4 = e4 % 48, l = e4 / 48;
        int db = 4*d4;
        float4 v  = *(float4*)&buf[l*196 + db];
        float4 g4 = *(const float4*)&lng[db];
        float4 b4 = *(const float4*)&lnb[db];
        float4 z4 = *(const float4*)&z_silu[((size_t)(b*LL + l0 + l))*DIN + db];
        float mu = lmu[l], rs = lrs[l];
        v.x = ((v.x - mu)*rs*g4.x + b4.x) * z4.x;
        v.y = ((v.y - mu)*rs*g4.y + b4.y) * z4.y;
        v.z = ((v.z - mu)*rs*g4.z + b4.z) * z4.z;
        v.w = ((v.w - mu)*rs*g4.w + b4.w) * z4.w;
        *(float4*)&buf[l*196 + db] = v;
    }
    int l = t & 15;
    int c0 = (t >> 4) * 6;
    float acc[6];
    #pragma unroll
    for (int cc = 0; cc < 6; ++cc) acc[cc] = 0.f;
    for (int p = 0; p < 2; ++p) {
        __syncthreads();
        for (int i = 0; i < 9; ++i) {
            int e4 = t + 256*i;          // 2304 float4 = 96cc x 24dd4
            int dd4 = e4 % 24, cc = e4 / 24;
            *(float4*)&lwout[cc*100 + 4*dd4] =
                *(const float4*)&Wout[(size_t)cc*DIN + p*96 + 4*dd4];
        }
        __syncthreads();
        for (int d4 = 0; d4 < 24; ++d4) {
            float4 v = *(float4*)&buf[l*196 + p*96 + 4*d4];
            #pragma unroll
            for (int cc = 0; cc < 6; ++cc) {
                float4 w = *(const float4*)&lwout[(c0 + cc)*100 + 4*d4];
                acc[cc] += v.x*w.x + v.y*w.y + v.z*w.z + v.w*w.w;
            }
        }
    }
    #pragma unroll
    for (int cc = 0; cc < 6; ++cc)
        out[((size_t)(b*LL + l0 + l))*CC + c0 + cc] = acc[cc];
}

// ---------------------------------------------------------------------------
extern "C" void kernel_launch(void* const* d_in, const int* in_sizes, int n_in,
                              void* d_out, int out_size, void* d_ws, size_t ws_size,
                              hipStream_t stream) {
    const float* x      = (const float*)d_in[0];
    const float* W_in   = (const float*)d_in[1];
    const float* conv_w = (const float*)d_in[2];
    const float* conv_b = (const float*)d_in[3];
    const float* xpw    = (const float*)d_in[4];
    const float* dt_w   = (const float*)d_in[5];
    const float* dt_b   = (const float*)d_in[6];
    const float* A_logs = (const float*)d_in[7];
    const float* Ds     = (const float*)d_in[8];
    const float* gate_w = (const float*)d_in[9];
    const float* gate_b = (const float*)d_in[10];
    const float* ln_g   = (const float*)d_in[11];
    const float* ln_b   = (const float*)d_in[12];
    const float* W_out  = (const float*)d_in[13];
    float* out = (float*)d_out;

    // baseF = y_scan + z + xconv + xconvT + dts + Bs + Cs + pool = 12,323,840
    // @SEGC=128: + 2*3,145,728 -> 18,615,296 floats = 74.5 MB (r1 proved 78.1).
    const size_t baseF = 6291456ull + 3ull*1572864 + 262144ull + 2ull*524288 + 3072;
    int SEGC = 16;
    if ((baseF + 2ull*128*24576)*4 <= ws_size) SEGC = 128;
    else if ((baseF + 2ull*64*24576)*4 <= ws_size) SEGC = 64;
    else if ((baseF + 2ull*32*24576)*4 <= ws_size) SEGC = 32;
    int SL = LL / SEGC;
    size_t segF = (size_t)SEGC * 24576;

    float* ws      = (float*)d_ws;
    float* y_scan  = ws;
    float* xc_pre  = ws;                       // alias (dead after k_conv)
    float* z_silu  = y_scan  + 6291456;
    float* xconv   = z_silu  + 1572864;
    float* xconvT  = xconv   + 1572864;
    float* dts     = xconvT  + 1572864;        // [bk][p][8]
    float* Bs      = dts     + 262144;
    float* Cs      = Bs      + 524288;
    float* poolsum = Cs      + 524288;
    float* segA    = poolsum + 3072;
    float* segB    = segA    + segF;
    float* hinit   = segA;                     // ALIAS (scan2 is alias-safe)

    k_inproj<<<dim3(LL/32, BB, 2), 256, 0, stream>>>(x, W_in, xc_pre, z_silu);
    k_conv<<<(BB*LL*48)/256, 256, 0, stream>>>(xc_pre, conv_w, conv_b,
                                               xconv, xconvT);
    k_proj<<<dim3(LL/64, KK, BB), 512, 0, stream>>>(xconv, xconvT, xpw,
                                                    dts, Bs, Cs);
    k_scan1<<<dim3(SEGC, BB*KK), 384, 0, stream>>>(xconv, xconvT, Bs, Cs, dts,
                                                   dt_w, dt_b, A_logs, Ds,
                                                   y_scan, segA, segB, SL);
    k_scan2<<<(BB*KK*DIN*NST + 255)/256, 256, 0, stream>>>(segA, segB, hinit,
                                                           poolsum, SEGC);
    k_apply<<<dim3(SEGC, BB*KK), 384, 0, stream>>>(Cs, dts, dt_w, dt_b,
                                                   A_logs, hinit,
                                                   y_scan, poolsum, SL);
    k_final<<<dim3(LL/16, BB), 256, 0, stream>>>(y_scan, poolsum, gate_w, gate_b,
                                                 z_silu, ln_g, ln_b, W_out, out);
}

// Round 14
// 264.986 us; speedup vs baseline: 1.0666x; 1.0666x over previous
//
#include <hip/hip_runtime.h>
#include <math.h>

#define BB 2
#define CC 96
#define DIN 192
#define NST 16
#define RNK 6
#define KK 4
#define LL 4096
#define RTOT (RNK + 2*NST)   // 38

// Scratch layouts:
//   xc_pre (aliases y_scan), z_silu, xconv : [b][l_spatial][DIN]
//   xconvT : [b][tp(l)][DIN]
//   dts    : [bk][p_scan][8]
//   Bs, Cs : [bk][p_scan][NST]
//   segA(/hinit alias)/segB : [bk][seg][d][NST]
//   y_scan : [bk][p_scan][DIN]
// Analytic maps: k=0: l=p; k=1: xconvT row p; k=2: l=LL-1-p; k=3: xconvT row LL-1-p
// inverse: p = {l, tp(l), LL-1-l, LL-1-tp(l)}, tp(l) = (l&63)*64 + (l>>6)

// ---------------------------------------------------------------------------
// K1: in_proj. grid (L/32, B, z). Block 256 = 8 lg (4 l) x 32 og (6 oc).
__global__ __launch_bounds__(256) void k_inproj(const float* __restrict__ x,
        const float* __restrict__ W_in, float* __restrict__ xc_pre,
        float* __restrict__ z_silu) {
    __shared__ float lx[96*33];
    __shared__ float wt[48*196];
    int b = blockIdx.y, z = blockIdx.z;
    int l0 = blockIdx.x * 32;
    int t = threadIdx.x;
    for (int i = 0; i < 3; ++i) {
        int e4 = t + 256*i;
        int c4 = e4 % 24, l = e4 / 24;
        float4 v = *(const float4*)&x[((size_t)(b*LL + l0 + l))*96 + 4*c4];
        lx[(4*c4+0)*33 + l] = v.x;
        lx[(4*c4+1)*33 + l] = v.y;
        lx[(4*c4+2)*33 + l] = v.z;
        lx[(4*c4+3)*33 + l] = v.w;
    }
    int lg = t & 7;
    int og = t >> 3;
    float acc[4][6];
    #pragma unroll
    for (int j = 0; j < 4; ++j)
        #pragma unroll
        for (int q = 0; q < 6; ++q) acc[j][q] = 0.f;
    for (int p = 0; p < 2; ++p) {
        __syncthreads();
        for (int i = 0; i < 9; ++i) {
            int e4 = t + 256*i;
            int cc4 = e4 % 12, oc = e4 / 12;
            float4 v = *(const float4*)&W_in[((size_t)(z*192 + oc))*96 + p*48 + 4*cc4];
            wt[(4*cc4+0)*196 + oc] = v.x;
            wt[(4*cc4+1)*196 + oc] = v.y;
            wt[(4*cc4+2)*196 + oc] = v.z;
            wt[(4*cc4+3)*196 + oc] = v.w;
        }
        __syncthreads();
        #pragma unroll 4
        for (int cc = 0; cc < 48; ++cc) {
            int c = p*48 + cc;
            float x0 = lx[c*33 + 4*lg + 0];
            float x1 = lx[c*33 + 4*lg + 1];
            float x2 = lx[c*33 + 4*lg + 2];
            float x3 = lx[c*33 + 4*lg + 3];
            const float* wr = &wt[cc*196 + 6*og];
            float2 w0 = *(const float2*)(wr);
            float2 w1 = *(const float2*)(wr + 2);
            float2 w2 = *(const float2*)(wr + 4);
            float wv[6] = {w0.x,w0.y, w1.x,w1.y, w2.x,w2.y};
            #pragma unroll
            for (int q = 0; q < 6; ++q) {
                acc[0][q] += x0*wv[q];
                acc[1][q] += x1*wv[q];
                acc[2][q] += x2*wv[q];
                acc[3][q] += x3*wv[q];
            }
        }
    }
    float* dst = (z == 0) ? xc_pre : z_silu;
    #pragma unroll
    for (int j = 0; j < 4; ++j) {
        int l = l0 + 4*lg + j;
        size_t base = (size_t)(b*LL + l)*DIN + 6*og;
        float v[6];
        #pragma unroll
        for (int q = 0; q < 6; ++q) {
            float a = acc[j][q];
            v[q] = z ? a/(1.f + __expf(-a)) : a;
        }
        *(float2*)&dst[base]     = make_float2(v[0], v[1]);
        *(float2*)&dst[base + 2] = make_float2(v[2], v[3]);
        *(float2*)&dst[base + 4] = make_float2(v[4], v[5]);
    }
}

// ---------------------------------------------------------------------------
// K2: depthwise 3x3 conv + bias + SiLU; writes spatial + transposed layouts.
__global__ __launch_bounds__(256) void k_conv(const float* __restrict__ xc,
        const float* __restrict__ cw, const float* __restrict__ cb,
        float* __restrict__ out, float* __restrict__ outT) {
    int gid = blockIdx.x*256 + threadIdx.x;
    int dq = gid % 48;
    int r = gid / 48;
    int l = r & 4095, b = r >> 12;
    int w = l & 63, h = l >> 6;
    int d0 = dq*4;
    float4 acc = *(const float4*)&cb[d0];
    float wreg[4][9];
    #pragma unroll
    for (int j = 0; j < 4; ++j)
        #pragma unroll
        for (int tp = 0; tp < 9; ++tp) wreg[j][tp] = cw[(d0+j)*9 + tp];
    #pragma unroll
    for (int dh = -1; dh <= 1; ++dh) {
        int h2 = h + dh;
        bool okh = (h2 >= 0) && (h2 < 64);
        #pragma unroll
        for (int dw = -1; dw <= 1; ++dw) {
            int w2 = w + dw;
            if (okh && w2 >= 0 && w2 < 64) {
                float4 v = *(const float4*)&xc[((size_t)(b*LL + h2*64 + w2))*DIN + d0];
                int tp = (dh+1)*3 + (dw+1);
                acc.x += v.x*wreg[0][tp];
                acc.y += v.y*wreg[1][tp];
                acc.z += v.z*wreg[2][tp];
                acc.w += v.w*wreg[3][tp];
            }
        }
    }
    float4 o;
    o.x = acc.x/(1.f + __expf(-acc.x));
    o.y = acc.y/(1.f + __expf(-acc.y));
    o.z = acc.z/(1.f + __expf(-acc.z));
    o.w = acc.w/(1.f + __expf(-acc.w));
    *(float4*)&out[((size_t)(b*LL + l))*DIN + d0] = o;
    int lt = w*64 + h;
    *(float4*)&outT[((size_t)(b*LL + lt))*DIN + d0] = o;
}

// ---------------------------------------------------------------------------
// K3: x_proj GEMV -> dts + Bs/Cs. Analytic contiguous gather.
__global__ __launch_bounds__(512) void k_proj(const float* __restrict__ xconv,
        const float* __restrict__ xconvT, const float* __restrict__ xpw,
        float* __restrict__ dts, float* __restrict__ Bs, float* __restrict__ Cs) {
    __shared__ float lxs[96*65];
    __shared__ float lw[RTOT*96];
    __shared__ float lbc[64*33];
    int k = blockIdx.y, b = blockIdx.z;
    int l0 = blockIdx.x * 64;
    int t = threadIdx.x;
    const float* src = (k & 1) ? xconvT : xconv;
    int rb = (k < 2) ? l0 : (LL - 1 - l0);
    int rs = (k < 2) ? 1 : -1;
    int l = t & 63;
    int rg = __builtin_amdgcn_readfirstlane(t >> 6);
    float acc[5];
    #pragma unroll
    for (int j = 0; j < 5; ++j) acc[j] = 0.f;
    for (int p = 0; p < 2; ++p) {
        __syncthreads();
        for (int i = 0; i < 3; ++i) {
            int e4 = t + 512*i;
            int dd4 = e4 % 24, ll = e4 / 24;
            int row = rb + rs*ll;
            float4 v = *(const float4*)&src[((size_t)(b*LL + row))*DIN + p*96 + 4*dd4];
            lxs[(4*dd4+0)*65 + ll] = v.x;
            lxs[(4*dd4+1)*65 + ll] = v.y;
            lxs[(4*dd4+2)*65 + ll] = v.z;
            lxs[(4*dd4+3)*65 + ll] = v.w;
        }
        for (int i = 0; i < 2; ++i) {
            int e4 = t + 512*i;
            if (e4 < RTOT*24) {
                int r = e4 / 24, dd4 = e4 % 24;
                *(float4*)&lw[r*96 + 4*dd4] =
                    *(const float4*)&xpw[(size_t)k*RTOT*DIN + r*DIN + p*96 + 4*dd4];
            }
        }
        __syncthreads();
        for (int dd = 0; dd < 96; dd += 4) {
            float x0 = lxs[(dd+0)*65 + l];
            float x1 = lxs[(dd+1)*65 + l];
            float x2 = lxs[(dd+2)*65 + l];
            float x3 = lxs[(dd+3)*65 + l];
            #pragma unroll
            for (int j = 0; j < 5; ++j) {
                int r = rg + 8*j;
                if (r < RTOT) {
                    float4 w = *(const float4*)&lw[r*96 + dd];
                    acc[j] += x0*w.x + x1*w.y + x2*w.z + x3*w.w;
                }
            }
        }
    }
    int bk = b*KK + k;
    #pragma unroll
    for (int j = 0; j < 5; ++j) {
        int r = rg + 8*j;
        if (r < RNK)       dts[((size_t)bk*LL + l0 + l)*8 + r] = acc[j];
        else if (r < RTOT) lbc[l*33 + (r - RNK)] = acc[j];
    }
    __syncthreads();
    size_t rowb = ((size_t)bk*LL + l0)*NST;
    for (int i = 0; i < 2; ++i) {
        int e = t + 512*i;
        int n = e & 15, ll = e >> 4;
        Bs[rowb + ll*NST + n] = lbc[ll*33 + n];
        Cs[rowb + ll*NST + n] = lbc[ll*33 + 16 + n];
    }
}

// ---------------------------------------------------------------------------
// K4: heavy scan pass (h0 = 0). BULK-coalesced: B/C/dts staged into LDS as one
// float4 burst per 32-li chunk; y accumulated in a 24 KB LDS tile and flushed
// full-width. Only per-li global access is the (contiguous, L2-warm) x row.
__global__ __launch_bounds__(384) void k_scan1(const float* __restrict__ xconv,
        const float* __restrict__ xconvT,
        const float* __restrict__ Bs, const float* __restrict__ Cs,
        const float* __restrict__ dts, const float* __restrict__ dtw,
        const float* __restrict__ dtb,
        const float* __restrict__ A_logs, const float* __restrict__ Ds,
        float* __restrict__ y_scan, float* __restrict__ segA,
        float* __restrict__ segB, int SL) {
    __shared__ float sB[32*NST];      // 2 KB
    __shared__ float sC[32*NST];      // 2 KB
    __shared__ float sD[32*8];        // 1 KB
    __shared__ float sY[32*DIN];      // 24 KB
    int seg = blockIdx.x, bk = blockIdx.y;
    int b = bk >> 2, k = bk & 3;
    int t = threadIdx.x;
    int half = t & 1, d = t >> 1;
    int l0 = seg * SL;
    const float* src = (k & 1) ? xconvT : xconv;
    int rb = (k < 2) ? l0 : (LL - 1 - l0);
    int rs = (k < 2) ? 1 : -1;
    float Av[8];
    {
        const float4* ap = (const float4*)(A_logs + ((k*DIN + d)*NST + half*8));
        float4 a0 = ap[0], a1 = ap[1];
        Av[0]=-__expf(a0.x); Av[1]=-__expf(a0.y); Av[2]=-__expf(a0.z); Av[3]=-__expf(a0.w);
        Av[4]=-__expf(a1.x); Av[5]=-__expf(a1.y); Av[6]=-__expf(a1.z); Av[7]=-__expf(a1.w);
    }
    float Av0 = -__expf(A_logs[(k*DIN + d)*NST]);
    bool okl = true;
    #pragma unroll
    for (int q = 0; q < 8; ++q) {
        float m = (float)(half*8 + q + 1);
        okl = okl && (fabsf(Av[q] - m*Av0) <= 1e-4f*m);
    }
    int fast = __all(okl);
    float Dv = Ds[k*DIN + d];
    float wdt[RNK];
    float bdt = dtb[k*DIN + d];
    #pragma unroll
    for (int r = 0; r < RNK; ++r) wdt[r] = dtw[(k*DIN + d)*RNK + r];
    float h[8];
    #pragma unroll
    for (int n = 0; n < 8; ++n) h[n] = 0.f;
    float sumdv = 0.f;
    float xn = src[((size_t)(b*LL + rb))*DIN + d];
    for (int c0 = 0; c0 < SL; c0 += 32) {
        // --- stage chunk: 320 float4 = 1280 floats, one coalesced burst ---
        if (t < 128) {
            *(float4*)&sB[4*t] =
                *(const float4*)&Bs[((size_t)bk*LL + l0 + c0)*NST + 4*t];
        } else if (t < 256) {
            int u = t - 128;
            *(float4*)&sC[4*u] =
                *(const float4*)&Cs[((size_t)bk*LL + l0 + c0)*NST + 4*u];
        } else if (t < 320) {
            int u = t - 256;
            *(float4*)&sD[4*u] =
                *(const float4*)&dts[((size_t)bk*LL + l0 + c0)*8 + 4*u];
        }
        __syncthreads();
        for (int li2 = 0; li2 < 32; ++li2) {
            int li = c0 + li2;
            float xv = xn;
            if (li + 1 < SL) {
                int row = rb + rs*(li + 1);
                xn = src[((size_t)(b*LL + row))*DIN + d];
            }
            float aa = bdt;
            #pragma unroll
            for (int r = 0; r < RNK; ++r) aa += sD[li2*8 + r]*wdt[r];
            float dv = fmaxf(aa, 0.f) + __logf(1.f + __expf(-fabsf(aa)));
            sumdv += dv;
            float dxv = dv * xv;
            float4 b0 = *(const float4*)&sB[li2*NST + half*8];
            float4 b1 = *(const float4*)&sB[li2*NST + half*8 + 4];
            float4 c0v = *(const float4*)&sC[li2*NST + half*8];
            float4 c1v = *(const float4*)&sC[li2*NST + half*8 + 4];
            float bb[8] = {b0.x,b0.y,b0.z,b0.w, b1.x,b1.y,b1.z,b1.w};
            float cc[8] = {c0v.x,c0v.y,c0v.z,c0v.w, c1v.x,c1v.y,c1v.z,c1v.w};
            float y = 0.f;
            if (fast) {
                float E  = __expf(dv * Av0);
                float E2 = E*E, E4 = E2*E2;
                float P[8];
                P[0] = E;      P[1] = E2;     P[2] = E2*E;    P[3] = E4;
                P[4] = E4*E;   P[5] = E4*E2;  P[6] = E4*P[2]; P[7] = E4*E4;
                float s = half ? P[7] : 1.0f;
                #pragma unroll
                for (int n = 0; n < 8; ++n) {
                    h[n] = (s*P[n])*h[n] + dxv*bb[n];
                    y += h[n]*cc[n];
                }
            } else {
                #pragma unroll
                for (int n = 0; n < 8; ++n) {
                    float e2 = __expf(dv * Av[n]);
                    h[n] = e2*h[n] + dxv*bb[n];
                    y += h[n]*cc[n];
                }
            }
            y += __shfl_xor(y, 1);
            if (half == 0) {
                sY[li2*DIN + d] = y + xv * Dv;
            }
        }
        __syncthreads();
        // --- flush y tile: 1536 float4, full-width coalesced ---
        size_t ybase = ((size_t)bk*LL + l0 + c0)*DIN;
        for (int i = 0; i < 4; ++i) {
            int e4 = t + 384*i;
            *(float4*)&y_scan[ybase + 4*e4] = *(const float4*)&sY[4*e4];
        }
        __syncthreads();
    }
    float a[8];
    #pragma unroll
    for (int n = 0; n < 8; ++n) a[n] = __expf(Av[n]*sumdv);
    size_t base = (((size_t)bk*gridDim.x + seg)*DIN + d)*NST + half*8;
    *(float4*)&segA[base]     = make_float4(a[0],a[1],a[2],a[3]);
    *(float4*)&segA[base + 4] = make_float4(a[4],a[5],a[6],a[7]);
    *(float4*)&segB[base]     = make_float4(h[0],h[1],h[2],h[3]);
    *(float4*)&segB[base + 4] = make_float4(h[4],h[5],h[6],h[7]);
}

// ---------------------------------------------------------------------------
// K5: compose segment carries (hinit aliases segA) + zero poolsum.
__global__ __launch_bounds__(256) void k_scan2(const float* segA,
        const float* segB, float* hinit, float* poolsum, int SEGC) {
    int idx = blockIdx.x*256 + threadIdx.x;
    if (idx < BB*DIN*KK) poolsum[idx] = 0.f;
    if (idx >= BB*KK*DIN*NST) return;
    int bk = idx / (DIN*NST);
    int dn = idx % (DIN*NST);
    const size_t stride = DIN*NST;
    size_t o = (size_t)bk*SEGC*stride + dn;
    float h = 0.f;
    for (int s = 0; s < SEGC; s += 8) {
        float av[8], bv[8];
        #pragma unroll
        for (int j = 0; j < 8; ++j) {
            av[j] = segA[o + j*stride];
            bv[j] = segB[o + j*stride];
        }
        #pragma unroll
        for (int j = 0; j < 8; ++j) {
            hinit[o + j*stride] = h;
            h = av[j]*h + bv[j];
        }
        o += 8*stride;
    }
}

// ---------------------------------------------------------------------------
// K6: h0 correction, bulk-coalesced: C/dts staged, y chunk staged into LDS
// (one float4 burst), RMW in LDS, flushed full-width.
__global__ __launch_bounds__(384) void k_apply(const float* __restrict__ Cs,
        const float* __restrict__ dts, const float* __restrict__ dtw,
        const float* __restrict__ dtb,
        const float* __restrict__ A_logs, const float* __restrict__ hinit,
        float* __restrict__ y_scan, float* __restrict__ poolsum, int SL) {
    __shared__ float sC[32*NST];      // 2 KB
    __shared__ float sD[32*8];        // 1 KB
    __shared__ float sY[32*DIN];      // 24 KB
    int seg = blockIdx.x, bk = blockIdx.y;
    int b = bk >> 2, k = bk & 3;
    int t = threadIdx.x;
    int half = t & 1, d = t >> 1;
    int l0 = seg * SL;
    float Av[8];
    {
        const float4* ap = (const float4*)(A_logs + ((k*DIN + d)*NST + half*8));
        float4 a0 = ap[0], a1 = ap[1];
        Av[0]=-__expf(a0.x); Av[1]=-__expf(a0.y); Av[2]=-__expf(a0.z); Av[3]=-__expf(a0.w);
        Av[4]=-__expf(a1.x); Av[5]=-__expf(a1.y); Av[6]=-__expf(a1.z); Av[7]=-__expf(a1.w);
    }
    float Av0 = -__expf(A_logs[(k*DIN + d)*NST]);
    bool okl = true;
    #pragma unroll
    for (int q = 0; q < 8; ++q) {
        float m = (float)(half*8 + q + 1);
        okl = okl && (fabsf(Av[q] - m*Av0) <= 1e-4f*m);
    }
    int fast = __all(okl);
    float h0[8];
    {
        size_t base = (((size_t)bk*gridDim.x + seg)*DIN + d)*NST + half*8;
        float4 v0 = *(const float4*)&hinit[base];
        float4 v1 = *(const float4*)&hinit[base + 4];
        h0[0]=v0.x; h0[1]=v0.y; h0[2]=v0.z; h0[3]=v0.w;
        h0[4]=v1.x; h0[5]=v1.y; h0[6]=v1.z; h0[7]=v1.w;
    }
    float wdt[RNK];
    float bdt = dtb[k*DIN + d];
    #pragma unroll
    for (int r = 0; r < RNK; ++r) wdt[r] = dtw[(k*DIN + d)*RNK + r];
    float cum = 0.f;
    float pool = 0.f;
    for (int c0 = 0; c0 < SL; c0 += 32) {
        // --- stage chunk: C + dts (192 float4) + y tile (1536 float4) ---
        if (t < 128) {
            *(float4*)&sC[4*t] =
                *(const float4*)&Cs[((size_t)bk*LL + l0 + c0)*NST + 4*t];
        } else if (t < 192) {
            int u = t - 128;
            *(float4*)&sD[4*u] =
                *(const float4*)&dts[((size_t)bk*LL + l0 + c0)*8 + 4*u];
        }
        size_t ybase = ((size_t)bk*LL + l0 + c0)*DIN;
        for (int i = 0; i < 4; ++i) {
            int e4 = t + 384*i;
            *(float4*)&sY[4*e4] = *(const float4*)&y_scan[ybase + 4*e4];
        }
        __syncthreads();
        for (int li2 = 0; li2 < 32; ++li2) {
            float aa = bdt;
            #pragma unroll
            for (int r = 0; r < RNK; ++r) aa += sD[li2*8 + r]*wdt[r];
            cum += fmaxf(aa, 0.f) + __logf(1.f + __expf(-fabsf(aa)));
            float4 c0v = *(const float4*)&sC[li2*NST + half*8];
            float4 c1v = *(const float4*)&sC[li2*NST + half*8 + 4];
            float cc[8] = {c0v.x,c0v.y,c0v.z,c0v.w, c1v.x,c1v.y,c1v.z,c1v.w};
            float g;
            if (fast) {
                float E = __expf(Av0 * cum);
                g = 0.f;
                #pragma unroll
                for (int q = 7; q >= 0; --q) g = g*E + cc[q]*h0[q];
                g *= E;
                if (half) {
                    float E2 = E*E, E4 = E2*E2;
                    g *= E4*E4;
                }
            } else {
                g = 0.f;
                #pragma unroll
                for (int q = 0; q < 8; ++q)
                    g += cc[q]*h0[q]*__expf(Av[q]*cum);
            }
            g += __shfl_xor(g, 1);
            if (half == 0) {
                float y = sY[li2*DIN + d] + g;
                sY[li2*DIN + d] = y;
                pool += y;
            }
        }
        __syncthreads();
        for (int i = 0; i < 4; ++i) {
            int e4 = t + 384*i;
            *(float4*)&y_scan[ybase + 4*e4] = *(const float4*)&sY[4*e4];
        }
        __syncthreads();
    }
    if (half == 0) atomicAdd(&poolsum[(b*DIN + d)*KK + k], pool);
}

// ---------------------------------------------------------------------------
// K7: gather y_scan via analytic inverse maps, gate, LN, silu(z), @ W_out^T.
__global__ __launch_bounds__(256) void k_final(const float* __restrict__ y_scan,
        const float* __restrict__ poolsum, const float* __restrict__ gw,
        const float* __restrict__ gb, const float* __restrict__ z_silu,
        const float* __restrict__ lng, const float* __restrict__ lnb,
        const float* __restrict__ Wout, float* __restrict__ out) {
    __shared__ float buf[16*196];
    __shared__ float lgate[DIN*KK];
    __shared__ float lwout[96*100];
    __shared__ float lmu[16], lrs[16];
    int b = blockIdx.y;
    int l0 = blockIdx.x * 16;
    int t = threadIdx.x;
    for (int e = t; e < DIN*KK; e += 256) {
        int d = e >> 2, o = e & 3;
        float acc = gb[d*KK + o];
        #pragma unroll
        for (int i = 0; i < KK; ++i)
            acc += (poolsum[(b*DIN + d)*KK + i] * (1.f/LL)) * gw[(d*KK + o)*KK + i];
        lgate[d*KK + o] = 1.f/(1.f + __expf(-acc));
    }
    __syncthreads();
    for (int i = 0; i < 3; ++i) {
        int e4 = t + 256*i;
        int d4 = e4 % 48, l = e4 / 48;
        int db = 4*d4;
        int ls = l0 + l;
        int tpl = ((ls & 63) << 6) | (ls >> 6);
        int pk[4] = {ls, tpl, LL - 1 - ls, LL - 1 - tpl};
        float4 acc = make_float4(0.f, 0.f, 0.f, 0.f);
        #pragma unroll
        for (int k = 0; k < KK; ++k) {
            float4 v = *(const float4*)&y_scan[((size_t)((b*KK + k)*LL + pk[k]))*DIN + db];
            acc.x += v.x * lgate[(db+0)*KK + k];
            acc.y += v.y * lgate[(db+1)*KK + k];
            acc.z += v.z * lgate[(db+2)*KK + k];
            acc.w += v.w * lgate[(db+3)*KK + k];
        }
        *(float4*)&buf[l*196 + db] = acc;
    }
    __syncthreads();
    int l2 = t >> 4, q = t & 15;
    float s = 0.f, s2 = 0.f;
    for (int i = 0; i < 12; ++i) {
        float v = buf[l2*196 + q + 16*i];
        s += v; s2 += v*v;
    }
    s += __shfl_xor(s, 1);  s2 += __shfl_xor(s2, 1);
    s += __shfl_xor(s, 2);  s2 += __shfl_xor(s2, 2);
    s += __shfl_xor(s, 4);  s2 += __shfl_xor(s2, 4);
    s += __shfl_xor(s, 8);  s2 += __shfl_xor(s2, 8);
    if (q == 0) {
        float mu = s * (1.f/DIN);
        float var = s2 * (1.f/DIN) - mu*mu;
        lmu[l2] = mu;
        lrs[l2] = rsqrtf(var + 1e-5f);
    }
    __syncthreads();
    for (int i = 0; i < 3; ++i) {
        int e4 = t + 256*i;
        int d4 = e4 % 48, l = e4 / 48;
        int db = 4*d4;
        float4 v  = *(float4*)&buf[l*196 + db];
        float4 g4 = *(const float4*)&lng[db];
        float4 b4 = *(const float4*)&lnb[db];
        float4 z4 = *(const float4*)&z_silu[((size_t)(b*LL + l0 + l))*DIN + db];
        float mu = lmu[l], rs = lrs[l];
        v.x = ((v.x - mu)*rs*g4.x + b4.x) * z4.x;
        v.y = ((v.y - mu)*rs*g4.y + b4.y) * z4.y;
        v.z = ((v.z - mu)*rs*g4.z + b4.z) * z4.z;
        v.w = ((v.w - mu)*rs*g4.w + b4.w) * z4.w;
        *(float4*)&buf[l*196 + db] = v;
    }
    int l = t & 15;
    int c0 = (t >> 4) * 6;
    float acc[6];
    #pragma unroll
    for (int cc = 0; cc < 6; ++cc) acc[cc] = 0.f;
    for (int p = 0; p < 2; ++p) {
        __syncthreads();
        for (int i = 0; i < 9; ++i) {
            int e4 = t + 256*i;
            int dd4 = e4 % 24, cc = e4 / 24;
            *(float4*)&lwout[cc*100 + 4*dd4] =
                *(const float4*)&Wout[(size_t)cc*DIN + p*96 + 4*dd4];
        }
        __syncthreads();
        for (int d4 = 0; d4 < 24; ++d4) {
            float4 v = *(float4*)&buf[l*196 + p*96 + 4*d4];
            #pragma unroll
            for (int cc = 0; cc < 6; ++cc) {
                float4 w = *(const float4*)&lwout[(c0 + cc)*100 + 4*d4];
                acc[cc] += v.x*w.x + v.y*w.y + v.z*w.z + v.w*w.w;
            }
        }
    }
    #pragma unroll
    for (int cc = 0; cc < 6; ++cc)
        out[((size_t)(b*LL + l0 + l))*CC + c0 + cc] = acc[cc];
}

// ---------------------------------------------------------------------------
extern "C" void kernel_launch(void* const* d_in, const int* in_sizes, int n_in,
                              void* d_out, int out_size, void* d_ws, size_t ws_size,
                              hipStream_t stream) {
    const float* x      = (const float*)d_in[0];
    const float* W_in   = (const float*)d_in[1];
    const float* conv_w = (const float*)d_in[2];
    const float* conv_b = (const float*)d_in[3];
    const float* xpw    = (const float*)d_in[4];
    const float* dt_w   = (const float*)d_in[5];
    const float* dt_b   = (const float*)d_in[6];
    const float* A_logs = (const float*)d_in[7];
    const float* Ds     = (const float*)d_in[8];
    const float* gate_w = (const float*)d_in[9];
    const float* gate_b = (const float*)d_in[10];
    const float* ln_g   = (const float*)d_in[11];
    const float* ln_b   = (const float*)d_in[12];
    const float* W_out  = (const float*)d_in[13];
    float* out = (float*)d_out;

    const size_t baseF = 6291456ull + 3ull*1572864 + 262144ull + 2ull*524288 + 3072;
    int SEGC = 16;
    if ((baseF + 2ull*128*24576)*4 <= ws_size) SEGC = 128;
    else if ((baseF + 2ull*64*24576)*4 <= ws_size) SEGC = 64;
    else if ((baseF + 2ull*32*24576)*4 <= ws_size) SEGC = 32;
    int SL = LL / SEGC;
    size_t segF = (size_t)SEGC * 24576;

    float* ws      = (float*)d_ws;
    float* y_scan  = ws;
    float* xc_pre  = ws;                       // alias (dead after k_conv)
    float* z_silu  = y_scan  + 6291456;
    float* xconv   = z_silu  + 1572864;
    float* xconvT  = xconv   + 1572864;
    float* dts     = xconvT  + 1572864;
    float* Bs      = dts     + 262144;
    float* Cs      = Bs      + 524288;
    float* poolsum = Cs      + 524288;
    float* segA    = poolsum + 3072;
    float* segB    = segA    + segF;
    float* hinit   = segA;                     // ALIAS (scan2 is alias-safe)

    k_inproj<<<dim3(LL/32, BB, 2), 256, 0, stream>>>(x, W_in, xc_pre, z_silu);
    k_conv<<<(BB*LL*48)/256, 256, 0, stream>>>(xc_pre, conv_w, conv_b,
                                               xconv, xconvT);
    k_proj<<<dim3(LL/64, KK, BB), 512, 0, stream>>>(xconv, xconvT, xpw,
                                                    dts, Bs, Cs);
    k_scan1<<<dim3(SEGC, BB*KK), 384, 0, stream>>>(xconv, xconvT, Bs, Cs, dts,
                                                   dt_w, dt_b, A_logs, Ds,
                                                   y_scan, segA, segB, SL);
    k_scan2<<<(BB*KK*DIN*NST + 255)/256, 256, 0, stream>>>(segA, segB, hinit,
                                                           poolsum, SEGC);
    k_apply<<<dim3(SEGC, BB*KK), 384, 0, stream>>>(Cs, dts, dt_w, dt_b,
                                                   A_logs, hinit,
                                                   y_scan, poolsum, SL);
    k_final<<<dim3(LL/16, BB), 256, 0, stream>>>(y_scan, poolsum, gate_w, gate_b,
                                                 z_silu, ln_g, ln_b, W_out, out);
}